// Round 2
// baseline (401.895 us; speedup 1.0000x reference)
//
#include <hip/hip_runtime.h>

#define BLOCK 1024
#define EPB 32        // batch elements per block
#define LDK 136       // padded LDS row stride in bf16 elements (128+8)

typedef __attribute__((ext_vector_type(8))) short short8;   // 8 bf16 = 4 VGPRs (MFMA A/B frag)
typedef __attribute__((ext_vector_type(4))) float f32x4;    // MFMA C/D frag

__device__ __forceinline__ unsigned short f2bf(float f) {
    unsigned u = __float_as_uint(f);
    u += 0x7FFF + ((u >> 16) & 1);    // round-to-nearest-even
    return (unsigned short)(u >> 16);
}

#define RED16(p) { p += __shfl_xor(p, 1); p += __shfl_xor(p, 2); \
                   p += __shfl_xor(p, 4); p += __shfl_xor(p, 8); }

// grid=512, BLOCK=1024 -> 2 blocks/CU = 32 waves/CU (8/SIMD, max occupancy).
// One block: 32 batch elements. Gather: exactly one float4 per thread.
// MFMA: 16 waves, each one 16x16 tile (16 elements x 16 hidden), 4 k-steps.
__global__ __launch_bounds__(BLOCK, 8) void mf_fused(
    const int* __restrict__ users, const int* __restrict__ items,
    const float* __restrict__ user_emb, const float* __restrict__ item_emb,
    const float* __restrict__ user_bias, const float* __restrict__ item_bias,
    const float* __restrict__ global_bias,
    const float* __restrict__ w1, const float* __restrict__ b1,
    const float* __restrict__ w2, const float* __restrict__ b2,
    float* __restrict__ out)
{
    __shared__ unsigned short sA[EPB * LDK];   // mlp_in (bf16) [e][k], k: 0..63 user, 64..127 item
    __shared__ unsigned short sB[128 * LDK];   // W1     (bf16) [h][k]
    __shared__ int   sUid[EPB], sIid[EPB];
    __shared__ float sBias[EPB];               // user_bias + item_bias + global_bias + b2
    __shared__ float sDot[EPB];                // fp32 dot
    __shared__ float sP[8][EPB];               // per-n-sixteenth MLP partials
    __shared__ float sB1[128];
    __shared__ float sW2[128];

    const int tid = threadIdx.x;
    const int e0 = blockIdx.x * EPB;

    // ---- issue index loads first (longest dependence chain: idx -> gather) ----
    int uid = 0, iid = 0;
    if (tid < EPB) { uid = users[e0 + tid]; iid = items[e0 + tid]; }
    if (tid < 128) { sB1[tid] = b1[tid]; sW2[tid] = w2[tid]; }

    // ---- stage W1 -> sB as bf16 [h][k]; independent L2 loads fill idx latency ----
    {
        const int c2 = tid & 31;     // float4 chunk within a 128-float row
        const int h0 = tid >> 5;     // 0..31
        #pragma unroll
        for (int it = 0; it < 4; ++it) {
            const int h = h0 + it * 32;
            const float4 wv = *(const float4*)(w1 + h * 128 + c2 * 4);
            ushort4 pk;
            pk.x = f2bf(wv.x); pk.y = f2bf(wv.y); pk.z = f2bf(wv.z); pk.w = f2bf(wv.w);
            *(ushort4*)&sB[h * LDK + c2 * 4] = pk;
        }
    }

    if (tid < EPB) { sUid[tid] = uid; sIid[tid] = iid; }
    __syncthreads();

    // ---- gather: one float4 per thread. el = tid>>5; half bit4 (0=user,1=item);
    //      c = tid&15 chunk. Dot via shfl_xor(.,16) pairing + butterfly. ----
    {
        const int el   = tid >> 5;
        const int half = (tid >> 4) & 1;
        const int c    = tid & 15;
        const int idx  = half ? sIid[el] : sUid[el];
        const float* base = half ? item_emb : user_emb;
        const float4 a = *(const float4*)(base + (size_t)idx * 64 + c * 4);

        ushort4 pk;
        pk.x = f2bf(a.x); pk.y = f2bf(a.y); pk.z = f2bf(a.z); pk.w = f2bf(a.w);
        *(ushort4*)&sA[el * LDK + half * 64 + c * 4] = pk;

        float4 o;
        o.x = __shfl_xor(a.x, 16); o.y = __shfl_xor(a.y, 16);
        o.z = __shfl_xor(a.z, 16); o.w = __shfl_xor(a.w, 16);
        float p = a.x * o.x + a.y * o.y + a.z * o.z + a.w * o.w;
        RED16(p)
        if ((tid & 31) == 0) sDot[el] = p;
    }

    // bias gathers (uid/iid already in registers for t<32)
    if (tid < EPB) {
        const float gb = global_bias[0] + b2[0];
        sBias[tid] = user_bias[uid] + item_bias[iid] + gb;
    }
    __syncthreads();

    // ---- MFMA: wave wv: m-half (wv&1)*16, hidden sixteenth (wv>>1)*16 ----
    const int lane  = tid & 63;
    const int wvid  = tid >> 6;        // 0..15
    const int quad  = lane >> 4;       // 0..3 (k-group)
    const int nidx  = lane & 15;
    const int mhalf = wvid & 1;
    const int n8    = wvid >> 1;       // 0..7
    const int hb    = n8 * 16;

    f32x4 acc = (f32x4){0.f, 0.f, 0.f, 0.f};
    #pragma unroll
    for (int kk = 0; kk < 4; ++kk) {
        const short8 a = *(const short8*)&sA[(mhalf * 16 + nidx) * LDK + kk * 32 + quad * 8];
        const short8 b = *(const short8*)&sB[(hb + nidx) * LDK + kk * 32 + quad * 8];
        acc = __builtin_amdgcn_mfma_f32_16x16x32_bf16(a, b, acc, 0, 0, 0);
    }

    // ---- epilogue: relu + w2 over this wave's 16 hidden; reduce over n-lanes ----
    {
        const int h = hb + nidx;
        const float b1v = sB1[h];
        const float w2v = sW2[h];
        float p0 = fmaxf(acc[0] + b1v, 0.f) * w2v;
        float p1 = fmaxf(acc[1] + b1v, 0.f) * w2v;
        float p2 = fmaxf(acc[2] + b1v, 0.f) * w2v;
        float p3 = fmaxf(acc[3] + b1v, 0.f) * w2v;
        RED16(p0) RED16(p1) RED16(p2) RED16(p3)
        if (nidx == 0) {
            const int eb = mhalf * 16 + quad * 4;   // D row m = quad*4 + r
            sP[n8][eb + 0] = p0;
            sP[n8][eb + 1] = p1;
            sP[n8][eb + 2] = p2;
            sP[n8][eb + 3] = p3;
        }
    }
    __syncthreads();

    if (tid < EPB) {
        float s = sDot[tid] + sBias[tid];
        #pragma unroll
        for (int k = 0; k < 8; ++k) s += sP[k][tid];
        out[e0 + tid] = s;
    }
}

extern "C" void kernel_launch(void* const* d_in, const int* in_sizes, int n_in,
                              void* d_out, int out_size, void* d_ws, size_t ws_size,
                              hipStream_t stream) {
    const int*   users       = (const int*)d_in[0];
    const int*   items       = (const int*)d_in[1];
    const float* user_emb    = (const float*)d_in[2];
    const float* item_emb    = (const float*)d_in[3];
    const float* user_bias   = (const float*)d_in[4];
    const float* item_bias   = (const float*)d_in[5];
    const float* global_bias = (const float*)d_in[6];
    const float* w1          = (const float*)d_in[7];
    const float* b1          = (const float*)d_in[8];
    const float* w2          = (const float*)d_in[9];
    const float* b2          = (const float*)d_in[10];
    float* out = (float*)d_out;

    const int batch = in_sizes[0];          // 16384
    const int grid = batch / EPB;           // 512 blocks, 1024 thr -> 32 waves/CU
    mf_fused<<<grid, BLOCK, 0, stream>>>(users, items, user_emb, item_emb,
        user_bias, item_bias, global_bias, w1, b1, w2, b2, out);
}